// Round 1
// baseline (593.731 us; speedup 1.0000x reference)
//
#include <hip/hip_runtime.h>
#include <hip/hip_bf16.h>
#include <math.h>

// MaskedSelfAttention: B=4, T=4096, D=1024, fp32 in/out, bf16 MFMA compute.
// Pipeline: cvt -> QK gemm -> Vt gemm -> S gemm (tri tiles + stats) ->
//           stats reduce -> P normalize -> O gemm.
// All GEMMs are m97-structure NT: 128x128 C-tile, 256 thr (4 waves, each 64x64
// as 4x4 of 16x16x32 bf16 MFMA), BK=32, global_load_lds width=16 staging.

typedef __bf16 bf16;
typedef __bf16 bf16x8 __attribute__((ext_vector_type(8)));
typedef float  f32x4  __attribute__((ext_vector_type(4)));

#define LOG2E 1.4426950408889634f

// ---------------- ws layout (bytes) ----------------
static constexpr size_t OFF_XB   = 0;            // [16384][1024] bf16   33.5MB
static constexpr size_t OFF_WQB  = 33554432;     // [1024][1024] bf16
static constexpr size_t OFF_WKB  = 35651584;
static constexpr size_t OFF_WVB  = 37748736;
static constexpr size_t OFF_Q    = 39845888;     // [4][4096][1024] bf16
static constexpr size_t OFF_K    = 73400320;
static constexpr size_t OFF_VT   = 106954752;    // [4][1024][4096] bf16
static constexpr size_t OFF_S    = 140509184;    // [4][528 tri tiles][128*128] bf16
static constexpr size_t OFF_PMAX = 209715200;    // [4][4096][32] f32
static constexpr size_t OFF_PSUM = 211812352;    // [4][4096][32] f32
static constexpr size_t OFF_MROW = 213909504;    // [16384] f32
static constexpr size_t OFF_LINV = 213975040;    // [16384] f32
// total ~214MB

// ---------------- helpers ----------------
typedef __attribute__((address_space(1))) void gvoid_t;
typedef __attribute__((address_space(3))) void lvoid_t;

__device__ __forceinline__ void gload16(const void* g, void* l) {
  // async global->LDS, 16B/lane; LDS dest = wave-uniform base + lane*16
  __builtin_amdgcn_global_load_lds((gvoid_t*)g, (lvoid_t*)l, 16, 0, 0);
}

struct Ctx { int tid, lane, quad, col16, wr, wc, wcol; };
__device__ __forceinline__ Ctx mk_ctx() {
  Ctx c; c.tid = (int)threadIdx.x; c.lane = c.tid & 63;
  int w = c.tid >> 6;
  c.quad = c.lane >> 4; c.col16 = c.lane & 15;
  c.wr = (w >> 1) * 64; c.wc = (w & 1) * 64; c.wcol = w & 1;
  return c;
}

// Stage a 128-row x 32-col bf16 tile (row stride ld elems) into sA[128][32].
// 8 chunks of 16 rows; wave w issues chunks 2w, 2w+1. LDS ends up row-major.
__device__ __forceinline__ void stage_tile(const bf16* g, long ld, bf16* s, int tid) {
  int lane = tid & 63, w = tid >> 6;
  const bf16* gp = g + (long)(lane >> 2) * ld + (long)(lane & 3) * 8;
  long step = 16 * ld;
  gload16(gp + (long)(2 * w) * step,     s + (2 * w) * 512);
  gload16(gp + (long)(2 * w + 1) * step, s + (2 * w + 1) * 512);
}

// One BK=32 K-step: 8 ds_read_b128 + 16 MFMA per wave.
__device__ __forceinline__ void mfma_step(const bf16* sA, const bf16* sB,
                                          const Ctx& c, f32x4 acc[4][4]) {
  bf16x8 a[4], b[4];
#pragma unroll
  for (int i = 0; i < 4; ++i) {
    a[i] = *(const bf16x8*)(sA + ((c.wr + i * 16 + c.col16) * 32 + c.quad * 8));
    b[i] = *(const bf16x8*)(sB + ((c.wc + i * 16 + c.col16) * 32 + c.quad * 8));
  }
#pragma unroll
  for (int i = 0; i < 4; ++i)
#pragma unroll
    for (int j = 0; j < 4; ++j)
      acc[i][j] = __builtin_amdgcn_mfma_f32_16x16x32_bf16(a[i], b[j], acc[i][j], 0, 0, 0);
}

__device__ __forceinline__ void zero_acc(f32x4 acc[4][4]) {
  f32x4 z = {0.f, 0.f, 0.f, 0.f};
#pragma unroll
  for (int i = 0; i < 4; ++i)
#pragma unroll
    for (int j = 0; j < 4; ++j) acc[i][j] = z;
}

__device__ __forceinline__ int tridec(int i) {
  int qt = (int)((sqrtf(8.0f * (float)i + 1.0f) - 1.0f) * 0.5f);
  while ((qt + 1) * (qt + 2) / 2 <= i) ++qt;
  while (qt * (qt + 1) / 2 > i) --qt;
  return qt;
}

// ---------------- kernels ----------------

__global__ __launch_bounds__(256) void cvtk(const float* __restrict__ in,
                                            bf16* __restrict__ out, long n) {
  long i = ((long)blockIdx.x * 256 + threadIdx.x) * 8;
  if (i + 8 > n) return;
  float4 f0 = *(const float4*)(in + i);
  float4 f1 = *(const float4*)(in + i + 4);
  bf16x8 h;
  h[0] = (bf16)f0.x; h[1] = (bf16)f0.y; h[2] = (bf16)f0.z; h[3] = (bf16)f0.w;
  h[4] = (bf16)f1.x; h[5] = (bf16)f1.y; h[6] = (bf16)f1.z; h[7] = (bf16)f1.w;
  *(bf16x8*)(out + i) = h;
}

// Q,K projection: C[m=t][n=e] = sum_d X[t][d]*W[e][d] + b[e].  z: 0=Q, 1=K
__global__ __launch_bounds__(256) void qk_gemm(const bf16* __restrict__ X,
                                               const bf16* __restrict__ Wq,
                                               const bf16* __restrict__ Wk,
                                               const float* __restrict__ bq,
                                               const float* __restrict__ bk,
                                               bf16* __restrict__ Q,
                                               bf16* __restrict__ K) {
  __shared__ __align__(16) bf16 sA[128 * 32], sB[128 * 32];
  Ctx c = mk_ctx();
  const bf16*  W    = blockIdx.z ? Wk : Wq;
  const float* bias = blockIdx.z ? bk : bq;
  bf16*        out  = blockIdx.z ? K : Q;
  long r0 = (long)blockIdx.y * 128, c0 = (long)blockIdx.x * 128;
  f32x4 acc[4][4]; zero_acc(acc);
  for (int k = 0; k < 1024; k += 32) {
    stage_tile(X + r0 * 1024 + k, 1024, sA, c.tid);
    stage_tile(W + c0 * 1024 + k, 1024, sB, c.tid);
    __syncthreads();
    mfma_step(sA, sB, c, acc);
    __syncthreads();
  }
#pragma unroll
  for (int j = 0; j < 4; ++j) {
    int col = c.wc + j * 16 + c.col16;
    float bb = bias[c0 + col];
#pragma unroll
    for (int i = 0; i < 4; ++i) {
      int rowb = c.wr + i * 16 + c.quad * 4;
#pragma unroll
      for (int r = 0; r < 4; ++r)
        out[(r0 + rowb + r) * 1024 + c0 + col] = (bf16)(acc[i][j][r] + bb);
    }
  }
}

// V transposed: C[m=e][n=t] = sum_d Wv[e][d]*X[z][t][d] + bv[e] -> Vt[z][e][t]
__global__ __launch_bounds__(256) void vt_gemm(const bf16* __restrict__ X,
                                               const bf16* __restrict__ Wv,
                                               const float* __restrict__ bv,
                                               bf16* __restrict__ Vt) {
  __shared__ __align__(16) bf16 sA[128 * 32], sB[128 * 32];
  Ctx c = mk_ctx();
  int z = blockIdx.z;
  long r0 = (long)blockIdx.y * 128;  // e
  long c0 = (long)blockIdx.x * 128;  // t
  const bf16* Ab = Wv + r0 * 1024;
  const bf16* Bb = X + (long)z * 4194304 + c0 * 1024;
  f32x4 acc[4][4]; zero_acc(acc);
  for (int k = 0; k < 1024; k += 32) {
    stage_tile(Ab + k, 1024, sA, c.tid);
    stage_tile(Bb + k, 1024, sB, c.tid);
    __syncthreads();
    mfma_step(sA, sB, c, acc);
    __syncthreads();
  }
  bf16* out = Vt + (long)z * 4194304;
#pragma unroll
  for (int i = 0; i < 4; ++i) {
    int rowb = c.wr + i * 16 + c.quad * 4;
    float bb[4];
#pragma unroll
    for (int r = 0; r < 4; ++r) bb[r] = bv[r0 + rowb + r];
#pragma unroll
    for (int j = 0; j < 4; ++j) {
      int col = c.wc + j * 16 + c.col16;
#pragma unroll
      for (int r = 0; r < 4; ++r)
        out[(r0 + rowb + r) * 4096 + c0 + col] = (bf16)(acc[i][j][r] + bb[r]);
    }
  }
}

// S = Q.K^T/32 on lower-tri 128x128 tiles; store raw bf16 (masked=-inf) +
// per-(row,tile) max and sumexp partials.
__global__ __launch_bounds__(256) void s_gemm(const bf16* __restrict__ Q,
                                              const bf16* __restrict__ K,
                                              bf16* __restrict__ S,
                                              float* __restrict__ pmax,
                                              float* __restrict__ psum) {
  __shared__ __align__(16) bf16 sA[128 * 32], sB[128 * 32];
  __shared__ float sred[2][128];
  __shared__ float srow[128];
  Ctx c = mk_ctx();
  int ti = blockIdx.x, z = blockIdx.z;
  int qt = tridec(ti);
  int kt = ti - qt * (qt + 1) / 2;
  long q0 = (long)qt * 128, k0 = (long)kt * 128;
  const bf16* Ab = Q + (long)z * 4194304 + q0 * 1024;
  const bf16* Bb = K + (long)z * 4194304 + k0 * 1024;
  f32x4 acc[4][4]; zero_acc(acc);
  for (int k = 0; k < 1024; k += 32) {
    stage_tile(Ab + k, 1024, sA, c.tid);
    stage_tile(Bb + k, 1024, sB, c.tid);
    __syncthreads();
    mfma_step(sA, sB, c, acc);
    __syncthreads();
  }
  bf16* st = S + ((long)z * 528 + ti) * 16384;
  const bool diag = (qt == kt);
  const float NI = -__builtin_inff();
  float rmx[4][4];
#pragma unroll
  for (int i = 0; i < 4; ++i)
#pragma unroll
    for (int r = 0; r < 4; ++r) rmx[i][r] = NI;
  // pass 1: scale, mask, round to bf16, store raw, track row max (of rounded)
#pragma unroll
  for (int i = 0; i < 4; ++i) {
#pragma unroll
    for (int r = 0; r < 4; ++r) {
      int row_l = c.wr + i * 16 + c.quad * 4 + r;
#pragma unroll
      for (int j = 0; j < 4; ++j) {
        int col_l = c.wc + j * 16 + c.col16;
        float v = acc[i][j][r] * 0.03125f;
        if (diag && col_l > row_l) v = NI;
        bf16 h = (bf16)v;
        st[row_l * 128 + col_l] = h;
        rmx[i][r] = fmaxf(rmx[i][r], (float)h);
      }
    }
  }
  // row max across the 16 col-lanes of this wave
#pragma unroll
  for (int i = 0; i < 4; ++i)
#pragma unroll
    for (int r = 0; r < 4; ++r)
      for (int m = 1; m <= 8; m <<= 1)
        rmx[i][r] = fmaxf(rmx[i][r], __shfl_xor(rmx[i][r], m));
  if (c.col16 == 0) {
#pragma unroll
    for (int i = 0; i < 4; ++i)
#pragma unroll
      for (int r = 0; r < 4; ++r)
        sred[c.wcol][c.wr + i * 16 + c.quad * 4 + r] = rmx[i][r];
  }
  __syncthreads();
  if (c.tid < 128) {
    float m = fmaxf(sred[0][c.tid], sred[1][c.tid]);
    srow[c.tid] = m;
    pmax[((long)z * 4096 + q0 + c.tid) * 32 + kt] = m;
  }
  __syncthreads();
  // pass 2: sumexp vs tile row max (recompute rounded values from acc)
  float rs[4][4];
#pragma unroll
  for (int i = 0; i < 4; ++i)
#pragma unroll
    for (int r = 0; r < 4; ++r) rs[i][r] = 0.f;
#pragma unroll
  for (int i = 0; i < 4; ++i) {
#pragma unroll
    for (int r = 0; r < 4; ++r) {
      int row_l = c.wr + i * 16 + c.quad * 4 + r;
      float rowm = srow[row_l];
#pragma unroll
      for (int j = 0; j < 4; ++j) {
        int col_l = c.wc + j * 16 + c.col16;
        float v = acc[i][j][r] * 0.03125f;
        if (diag && col_l > row_l) v = NI;
        float vr = (float)((bf16)v);
        rs[i][r] += exp2f((vr - rowm) * LOG2E);
      }
    }
  }
#pragma unroll
  for (int i = 0; i < 4; ++i)
#pragma unroll
    for (int r = 0; r < 4; ++r)
      for (int m = 1; m <= 8; m <<= 1)
        rs[i][r] += __shfl_xor(rs[i][r], m);
  __syncthreads();
  if (c.col16 == 0) {
#pragma unroll
    for (int i = 0; i < 4; ++i)
#pragma unroll
      for (int r = 0; r < 4; ++r)
        sred[c.wcol][c.wr + i * 16 + c.quad * 4 + r] = rs[i][r];
  }
  __syncthreads();
  if (c.tid < 128)
    psum[((long)z * 4096 + q0 + c.tid) * 32 + kt] = sred[0][c.tid] + sred[1][c.tid];
}

// combine per-tile partials -> per-row max m and 1/l
__global__ __launch_bounds__(256) void softmax_stats(const float* __restrict__ pmax,
                                                     const float* __restrict__ psum,
                                                     float* __restrict__ mrow,
                                                     float* __restrict__ linv) {
  long i = (long)blockIdx.x * 256 + threadIdx.x;  // 16384 rows
  int q = (int)(i & 4095);
  int nt = (q >> 7) + 1;
  const float* pm = pmax + i * 32;
  const float* ps = psum + i * 32;
  float m = -__builtin_inff();
  for (int t = 0; t < nt; ++t) m = fmaxf(m, pm[t]);
  float l = 0.f;
  for (int t = 0; t < nt; ++t) l += ps[t] * exp2f((pm[t] - m) * LOG2E);
  mrow[i] = m;
  linv[i] = 1.0f / l;
}

// P = exp(s - m)/l, in place on S tiles (bf16)
__global__ __launch_bounds__(256) void norm_p(bf16* __restrict__ S,
                                              const float* __restrict__ mrow,
                                              const float* __restrict__ linv) {
  int ti = blockIdx.x, z = blockIdx.z;
  int qt = tridec(ti);
  bf16* st = S + ((long)z * 528 + ti) * 16384;
  long qb = (long)z * 4096 + (long)qt * 128;
#pragma unroll
  for (int it = 0; it < 8; ++it) {
    int e0 = ((int)threadIdx.x + it * 256) * 8;
    int row = e0 >> 7;
    float m = mrow[qb + row];
    float li = linv[qb + row];
    bf16x8 v = *(const bf16x8*)(st + e0);
#pragma unroll
    for (int jj = 0; jj < 8; ++jj) {
      float s = (float)v[jj];
      v[jj] = (bf16)(exp2f((s - m) * LOG2E) * li);
    }
    *(bf16x8*)(st + e0) = v;
  }
}

// O[q][e] = sum_k P[q][k] * Vt[e][k], causal k bound; fp32 out
__global__ __launch_bounds__(256) void o_gemm(const bf16* __restrict__ S,
                                              const bf16* __restrict__ Vt,
                                              float* __restrict__ out) {
  __shared__ __align__(16) bf16 sA[128 * 32], sB[128 * 32];
  Ctx c = mk_ctx();
  int et = blockIdx.x, qt = blockIdx.y, z = blockIdx.z;
  long q0 = (long)qt * 128, e0 = (long)et * 128;
  const bf16* Bb = Vt + (long)z * 4194304 + e0 * 4096;
  long tribase = ((long)z * 528 + (long)qt * (qt + 1) / 2) * 16384;
  f32x4 acc[4][4]; zero_acc(acc);
  int kend = (qt + 1) * 128;
  for (int k = 0; k < kend; k += 32) {
    const bf16* Ab = S + tribase + (long)(k >> 7) * 16384 + (k & 127);
    stage_tile(Ab, 128, sA, c.tid);
    stage_tile(Bb + k, 4096, sB, c.tid);
    __syncthreads();
    mfma_step(sA, sB, c, acc);
    __syncthreads();
  }
#pragma unroll
  for (int i = 0; i < 4; ++i) {
    int rowb = c.wr + i * 16 + c.quad * 4;
#pragma unroll
    for (int j = 0; j < 4; ++j) {
      int col = c.wc + j * 16 + c.col16;
#pragma unroll
      for (int r = 0; r < 4; ++r)
        out[((long)z * 4096 + q0 + rowb + r) * 1024 + e0 + col] = acc[i][j][r];
    }
  }
}

// ---------------- launcher ----------------
extern "C" void kernel_launch(void* const* d_in, const int* in_sizes, int n_in,
                              void* d_out, int out_size, void* d_ws, size_t ws_size,
                              hipStream_t stream) {
  (void)in_sizes; (void)n_in; (void)out_size; (void)ws_size;
  const float* x  = (const float*)d_in[0];
  const float* Wq = (const float*)d_in[1];
  const float* bq = (const float*)d_in[2];
  const float* Wk = (const float*)d_in[3];
  const float* bk = (const float*)d_in[4];
  const float* Wv = (const float*)d_in[5];
  const float* bv = (const float*)d_in[6];

  char* ws = (char*)d_ws;
  bf16*  xb   = (bf16*)(ws + OFF_XB);
  bf16*  wqb  = (bf16*)(ws + OFF_WQB);
  bf16*  wkb  = (bf16*)(ws + OFF_WKB);
  bf16*  wvb  = (bf16*)(ws + OFF_WVB);
  bf16*  Qb   = (bf16*)(ws + OFF_Q);
  bf16*  Kb   = (bf16*)(ws + OFF_K);
  bf16*  Vtb  = (bf16*)(ws + OFF_VT);
  bf16*  Sb   = (bf16*)(ws + OFF_S);
  float* pmax = (float*)(ws + OFF_PMAX);
  float* psum = (float*)(ws + OFF_PSUM);
  float* mrow = (float*)(ws + OFF_MROW);
  float* linv = (float*)(ws + OFF_LINV);

  cvtk<<<8192, 256, 0, stream>>>(x,  xb,  16777216L);
  cvtk<<<512,  256, 0, stream>>>(Wq, wqb, 1048576L);
  cvtk<<<512,  256, 0, stream>>>(Wk, wkb, 1048576L);
  cvtk<<<512,  256, 0, stream>>>(Wv, wvb, 1048576L);

  qk_gemm<<<dim3(8, 128, 2), 256, 0, stream>>>(xb, wqb, wkb, bq, bk, Qb, Kb);
  vt_gemm<<<dim3(32, 8, 4), 256, 0, stream>>>(xb, wvb, bv, Vtb);
  s_gemm<<<dim3(528, 1, 4), 256, 0, stream>>>(Qb, Kb, Sb, pmax, psum);
  softmax_stats<<<64, 256, 0, stream>>>(pmax, psum, mrow, linv);
  norm_p<<<dim3(528, 1, 4), 256, 0, stream>>>(Sb, mrow, linv);
  o_gemm<<<dim3(8, 32, 4), 256, 0, stream>>>(Sb, Vtb, (float*)d_out);
}